// Round 1
// baseline (273.900 us; speedup 1.0000x reference)
//
#include <hip/hip_runtime.h>

// sparsemax over axis=2 of x[8][16][4096][64] (fp32).
// 8192 vectors of length 4096, stride 64 floats.
//
// Design:
//  - 1 block (1024 thr) per (bh, d-tile-of-16): 512 blocks. d-tile 16 floats = one
//    full 64B line per row -> perfectly coalesced loads/stores (16 lines / wave inst).
//  - Thread t: dq = t&3 (float4 column), iblk = t>>2; holds rows i = iblk+256*s,
//    s=0..15 -> 16 float4 = 64 floats register-resident (single HBM read).
//  - Pass 1: per-vector max via segmented wave butterfly (xor 4..32 keeps dq class)
//    + LDS cross-wave.
//  - Pass 2: compact candidates (x > max-1) into per-vector LDS lists (tau >= max-1
//    so nothing else can be in the support). Gaussian data: ~10-20 per vector.
//  - Pass 3: Newton on f(tau)=sum relu(x-tau)-1, one wave per vector, shuffle
//    reductions only. Monotone-from-below => exact sparsemax threshold; bitwise
//    termination guard. Overflow (>256 candidates) -> correct global-reread fallback.
//  - Pass 4: out = max(x - tau, 0) from registers, coalesced stores.

#define C_CAP 256

__global__ __launch_bounds__(1024, 4)
void sparsemax_ax2_kernel(const float* __restrict__ x, float* __restrict__ out)
{
    const int b   = blockIdx.x;
    const int bh  = b >> 2;             // (batch*heads) slab 0..127
    const int d0  = (b & 3) << 4;       // 16 d's per block: 0,16,32,48

    const int t    = threadIdx.x;       // 0..1023
    const int lane = t & 63;
    const int wv   = t >> 6;            // 0..15
    const int dq   = t & 3;             // float4 column in d-tile
    const int iblk = t >> 2;            // 0..255

    __shared__ float list[16][C_CAP];   // candidate values per vector
    __shared__ float redbuf[256];       // 16 waves x 16 vectors partial maxes
    __shared__ float gmaxT[16];
    __shared__ float tauLDS[16];
    __shared__ int   cnt[16];

    const float4* __restrict__ x4 = reinterpret_cast<const float4*>(x);
    float4* __restrict__ o4       = reinterpret_cast<float4*>(out);

    const size_t slabrow = (size_t)bh * 4096;
    // float4-index of (row iblk, col d0+4*dq); row stride = 16 float4
    const size_t idx0 = (slabrow + (size_t)iblk) * 16 + (size_t)(d0 >> 2) + (size_t)dq;

    // ---- load: 16 float4 per thread, register resident ----
    float4 c[16];
#pragma unroll
    for (int s = 0; s < 16; ++s)
        c[s] = x4[idx0 + (size_t)s * 4096];   // i += 256 per step

    // ---- per-vector max ----
    float4 m = c[0];
#pragma unroll
    for (int s = 1; s < 16; ++s) {
        m.x = fmaxf(m.x, c[s].x);
        m.y = fmaxf(m.y, c[s].y);
        m.z = fmaxf(m.z, c[s].z);
        m.w = fmaxf(m.w, c[s].w);
    }
    // segmented butterfly: xor masks 4..32 stay within same-dq lane class (16 lanes)
#pragma unroll
    for (int mask = 4; mask <= 32; mask <<= 1) {
        m.x = fmaxf(m.x, __shfl_xor(m.x, mask));
        m.y = fmaxf(m.y, __shfl_xor(m.y, mask));
        m.z = fmaxf(m.z, __shfl_xor(m.z, mask));
        m.w = fmaxf(m.w, __shfl_xor(m.w, mask));
    }
    if (lane < 4) {                     // lane == its dq class here
        redbuf[wv * 16 + lane * 4 + 0] = m.x;
        redbuf[wv * 16 + lane * 4 + 1] = m.y;
        redbuf[wv * 16 + lane * 4 + 2] = m.z;
        redbuf[wv * 16 + lane * 4 + 3] = m.w;
    }
    __syncthreads();
    if (t < 16) {
        float g = redbuf[t];
#pragma unroll
        for (int w = 1; w < 16; ++w) g = fmaxf(g, redbuf[w * 16 + t]);
        gmaxT[t] = g;
        cnt[t]   = 0;
    }
    __syncthreads();

    // ---- candidate extraction: only x > gmax-1 can ever be in the support ----
    const int j0 = dq << 2;
    float4 T4;
    T4.x = gmaxT[j0 + 0] - 1.0f;
    T4.y = gmaxT[j0 + 1] - 1.0f;
    T4.z = gmaxT[j0 + 2] - 1.0f;
    T4.w = gmaxT[j0 + 3] - 1.0f;

#pragma unroll
    for (int s = 0; s < 16; ++s) {
        if (c[s].x > T4.x) { int p = atomicAdd(&cnt[j0+0], 1); if (p < C_CAP) list[j0+0][p] = c[s].x; }
        if (c[s].y > T4.y) { int p = atomicAdd(&cnt[j0+1], 1); if (p < C_CAP) list[j0+1][p] = c[s].y; }
        if (c[s].z > T4.z) { int p = atomicAdd(&cnt[j0+2], 1); if (p < C_CAP) list[j0+2][p] = c[s].z; }
        if (c[s].w > T4.w) { int p = atomicAdd(&cnt[j0+3], 1); if (p < C_CAP) list[j0+3][p] = c[s].w; }
    }
    __syncthreads();

    // ---- Newton from below (one wave per vector), exact for piecewise-linear f ----
    {
        const int j = wv;
        const int n = cnt[j];
        float tau = gmaxT[j] - 1.0f;
        if (n <= C_CAP) {
            for (int it = 0; it < 100; ++it) {
                float sv = 0.f, cc = 0.f;
                for (int p = lane; p < n; p += 64) {
                    float v = list[j][p];
                    if (v > tau) { sv += v; cc += 1.f; }
                }
#pragma unroll
                for (int mask = 1; mask <= 32; mask <<= 1) {
                    sv += __shfl_xor(sv, mask);
                    cc += __shfl_xor(cc, mask);
                }
                if (cc < 0.5f) break;                 // can't happen; safety
                float tn = (sv - 1.0f) / cc;
                tn = fmaxf(tn, tau);                  // enforce monotone ascent
                if (tn == tau) break;                 // fixed point reached
                tau = tn;
            }
        } else {
            // overflow fallback: re-read the whole vector from global (L3-warm). Rare.
            const float* vb = x + slabrow * 64 + (size_t)(d0 + j);
            for (int it = 0; it < 100; ++it) {
                float sv = 0.f, cc = 0.f;
                for (int p = lane; p < 4096; p += 64) {
                    float v = vb[(size_t)p * 64];
                    if (v > tau) { sv += v; cc += 1.f; }
                }
#pragma unroll
                for (int mask = 1; mask <= 32; mask <<= 1) {
                    sv += __shfl_xor(sv, mask);
                    cc += __shfl_xor(cc, mask);
                }
                if (cc < 0.5f) break;
                float tn = (sv - 1.0f) / cc;
                tn = fmaxf(tn, tau);
                if (tn == tau) break;
                tau = tn;
            }
        }
        if (lane == 0) tauLDS[j] = tau;
    }
    __syncthreads();

    // ---- output: relu(x - tau), coalesced stores from registers ----
    float4 tau4;
    tau4.x = tauLDS[j0 + 0];
    tau4.y = tauLDS[j0 + 1];
    tau4.z = tauLDS[j0 + 2];
    tau4.w = tauLDS[j0 + 3];
#pragma unroll
    for (int s = 0; s < 16; ++s) {
        float4 o;
        o.x = fmaxf(c[s].x - tau4.x, 0.f);
        o.y = fmaxf(c[s].y - tau4.y, 0.f);
        o.z = fmaxf(c[s].z - tau4.z, 0.f);
        o.w = fmaxf(c[s].w - tau4.w, 0.f);
        o4[idx0 + (size_t)s * 4096] = o;
    }
}

extern "C" void kernel_launch(void* const* d_in, const int* in_sizes, int n_in,
                              void* d_out, int out_size, void* d_ws, size_t ws_size,
                              hipStream_t stream)
{
    (void)n_in; (void)d_ws; (void)ws_size; (void)out_size;
    const float* x = (const float*)d_in[0];
    float* out     = (float*)d_out;
    const int total = in_sizes[0];            // 8*16*4096*64
    const int slabs = total / (4096 * 64);    // 128
    dim3 grid(slabs * 4), block(1024);
    hipLaunchKernelGGL(sparsemax_ax2_kernel, grid, block, 0, stream, x, out);
}